// Round 2
// baseline (589.537 us; speedup 1.0000x reference)
//
#include <hip/hip_runtime.h>
#include <stdint.h>

#define B_  16
#define C_  256
#define HW_ 4096
#define Hp  66
#define PP  4356   // 66*66
#define EPS_ 1e-5f

typedef unsigned short u16;
typedef unsigned int   u32;
typedef __attribute__((ext_vector_type(4))) float  f32x4;
typedef __attribute__((ext_vector_type(8))) __bf16 bf16x8;
typedef __attribute__((ext_vector_type(8))) u16    u16x8;

__device__ __forceinline__ float bf2f(u16 u){ u32 x = ((u32)u)<<16; float f; __builtin_memcpy(&f,&x,4); return f; }
__device__ __forceinline__ u16 f2bf(float f){ u32 x; __builtin_memcpy(&x,&f,4); u32 r = x + 0x7fffu + ((x>>16)&1u); return (u16)(r>>16); }

__device__ __forceinline__ void g2l16(const void* g, void* l){
  __builtin_amdgcn_global_load_lds((__attribute__((address_space(1))) void*)(void*)g,
                                   (__attribute__((address_space(3))) void*)l, 16, 0, 0);
}
__device__ __forceinline__ bf16x8 ldfrag(const u16* p){
  u16x8 r = *(const u16x8*)p;
  return __builtin_bit_cast(bf16x8, r);
}

// ---------------- K0: pad + transpose + cast x -> xpT[b][66*66][256] bf16 ----------------
__global__ __launch_bounds__(256) void k_pad(const float* __restrict__ x, u16* __restrict__ xpT){
  int bid = blockIdx.x; int b = bid/66, hh = bid - b*66; int tid = threadIdx.x;
  u16* rowbase = xpT + (size_t)(b*PP + hh*Hp)*C_;
  if(hh==0 || hh==65){
    u32* p = (u32*)rowbase;
    for(int i=tid;i<66*C_/2;i+=256) p[i]=0u;
    return;
  }
  if(tid<128) ((u32*)rowbase)[tid]=0u;                 // ww = 0 border
  else ((u32*)(rowbase + 65*C_))[tid-128]=0u;          // ww = 65 border
  int h = hh-1;
  __shared__ float Lt[64*65];
  for(int cc=0; cc<4; cc++){
    int c0=cc*64;
    int ci = tid>>2, w0 = (tid&3)*16;
    const float* xs = x + ((size_t)(b*C_ + c0+ci)*HW_) + h*64 + w0;
    for(int j=0;j<4;j++){
      float4 v = *(const float4*)(xs + j*4);
      Lt[ci*65 + w0 + j*4 + 0] = v.x;
      Lt[ci*65 + w0 + j*4 + 1] = v.y;
      Lt[ci*65 + w0 + j*4 + 2] = v.z;
      Lt[ci*65 + w0 + j*4 + 3] = v.w;
    }
    __syncthreads();
    int w = tid>>2, cj = (tid&3)*16;
    union { u16 u[16]; uint4 v[2]; } outu;
    for(int j=0;j<16;j++) outu.u[j] = f2bf(Lt[(cj+j)*65 + w]);
    uint4* dst = (uint4*)(rowbase + (size_t)(w+1)*C_ + c0 + cj);
    dst[0]=outu.v[0]; dst[1]=outu.v[1];
    __syncthreads();
  }
}

// ---------------- K1: repack weights/context to bf16, zero stats ----------------
__global__ __launch_bounds__(256) void k_repack(
    const float* __restrict__ conv_w, const float* __restrict__ wq, const float* __restrict__ wo,
    const float* __restrict__ wk, const float* __restrict__ wv, const float* __restrict__ ctx,
    u16* __restrict__ wBt, u16* __restrict__ wqB, u16* __restrict__ woB,
    u16* __restrict__ wkvB, u16* __restrict__ ctxB, float* __restrict__ stats){
  int i = blockIdx.x*256 + threadIdx.x;
  if(i < 589824){ int co = i/2304, k = i - co*2304; int t = k>>8, ci = k&255;
    wBt[i] = f2bf(conv_w[(co*256+ci)*9 + t]); return; }
  i -= 589824;
  if(i < 65536){ wqB[i] = f2bf(wq[i]); return; } i -= 65536;
  if(i < 65536){ woB[i] = f2bf(wo[i]); return; } i -= 65536;
  if(i < 196608){ wkvB[i] = f2bf(wk[i]); return; } i -= 196608;
  if(i < 196608){ wkvB[196608+i] = f2bf(wv[i]); return; } i -= 196608;
  if(i < 946176){ ctxB[i] = f2bf(ctx[i]); return; } i -= 946176;
  if(i < 512){ stats[i] = 0.f; }
}

// ---------------- K2: conv as implicit GEMM, BK=64, chunk-major LDS ----------------
// As/Bs layout: element (row, kchunk c in 0..7, e in 0..7) at [c*1024 + row*8 + e]
__global__ __launch_bounds__(256) void k_conv(const u16* __restrict__ xpT, const u16* __restrict__ wBt,
    const float* __restrict__ conv_b, u16* __restrict__ h, float* __restrict__ stats){
  __shared__ u16 As[128*64];
  __shared__ u16 Bs[128*64];
  int bid = blockIdx.x;
  int nt = bid & 1, mt = bid >> 1;
  int b = mt >> 5, hp = mt & 31;
  int co0 = nt*128;
  int tid = threadIdx.x;
  int w = tid>>6, lane = tid&63, ln = lane&15, qd = lane>>4;
  int wm = w>>1, wn = w&1;
  f32x4 acc[4][4] = {};
  for(int t=0;t<9;t++){
    int dy = (t*11)>>5, dx = t - dy*3;
    for(int ci=0; ci<256; ci+=64){
      #pragma unroll
      for(int j=0;j<4;j++){
        int u = w*4 + j;
        int c = u>>1, half = u&1;
        int row = half*64 + lane;
        int wp = row & 63, hr = row >> 6;
        g2l16(xpT + ((size_t)(b*PP + (hp*2 + hr + dy)*Hp + wp + dx)*C_ + ci + c*8),
              &As[u*512 + lane*8]);
        g2l16(wBt + ((size_t)(co0 + row)*2304 + t*256 + ci + c*8),
              &Bs[u*512 + lane*8]);
      }
      __syncthreads();
      #pragma unroll
      for(int kk=0;kk<2;kk++){
        bf16x8 af[4], bfv[4];
        #pragma unroll
        for(int mf=0;mf<4;mf++) af[mf] = ldfrag(&As[(kk*4+qd)*1024 + (wm*64+mf*16+ln)*8]);
        #pragma unroll
        for(int nf=0;nf<4;nf++) bfv[nf] = ldfrag(&Bs[(kk*4+qd)*1024 + (wn*64+nf*16+ln)*8]);
        #pragma unroll
        for(int mf=0;mf<4;mf++)
          #pragma unroll
          for(int nf=0;nf<4;nf++)
            acc[mf][nf] = __builtin_amdgcn_mfma_f32_16x16x32_bf16(af[mf], bfv[nf], acc[mf][nf], 0,0,0);
      }
      __syncthreads();
    }
  }
  float s0=0.f,q0=0.f,s1=0.f,q1=0.f;
  int p0 = hp*128;
  for(int mf=0;mf<4;mf++) for(int nf=0;nf<4;nf++){
    int nl = wn*64 + nf*16 + ln;
    float bias = conv_b[co0+nl];
    for(int r=0;r<4;r++){
      int ml = wm*64 + mf*16 + qd*4 + r;
      float v = acc[mf][nf][r] + bias;
      h[((size_t)(b*HW_ + p0 + ml))*C_ + co0 + nl] = f2bf(v);
      if(nf<2){ s0+=v; q0+=v*v; } else { s1+=v; q1+=v*v; }
    }
  }
  for(int off=32;off>=1;off>>=1){
    s0 += __shfl_down(s0,off,64); q0 += __shfl_down(q0,off,64);
    s1 += __shfl_down(s1,off,64); q1 += __shfl_down(q1,off,64);
  }
  if(lane==0){
    int g0 = (co0 + wn*64)>>5;
    atomicAdd(&stats[(b*8+g0)*2+0], s0);
    atomicAdd(&stats[(b*8+g0)*2+1], q0);
    atomicAdd(&stats[(b*8+g0+1)*2+0], s1);
    atomicAdd(&stats[(b*8+g0+1)*2+1], q1);
  }
}

// ---------------- K3: finalize GN stats ----------------
__global__ void k_stats(float* __restrict__ stats){
  int t = threadIdx.x;
  if(t<128){
    float s = stats[t*2], q = stats[t*2+1];
    float inv = 1.f/131072.f;
    float mean = s*inv;
    float var = q*inv - mean*mean;
    stats[256 + t*2]   = mean;
    stats[256 + t*2+1] = rsqrtf(var + EPS_);
  }
}

// ---------------- K4: GN + SiLU, in place on h ----------------
__global__ __launch_bounds__(256) void k_gnsilu(u16* __restrict__ hbuf, const float* __restrict__ stats,
      const float* __restrict__ gnw, const float* __restrict__ gnb){
  size_t i = ((size_t)blockIdx.x*256 + threadIdx.x)*4;
  int c0 = (int)(i & 255);
  size_t row = i >> 8;
  int b = (int)(row >> 12);
  int g = c0 >> 5;
  float mean = stats[256 + (b*8+g)*2];
  float rstd = stats[256 + (b*8+g)*2+1];
  u32* p = (u32*)(hbuf + i);
  u32 v0 = p[0], v1 = p[1];
  u16 in[4] = {(u16)(v0&0xffff),(u16)(v0>>16),(u16)(v1&0xffff),(u16)(v1>>16)};
  u16 outv[4];
  for(int j=0;j<4;j++){
    float v = bf2f(in[j]);
    v = (v-mean)*rstd*gnw[c0+j] + gnb[c0+j];
    float s = v/(1.f+__expf(-v));
    outv[j] = f2bf(s);
  }
  p[0] = (u32)outv[0] | ((u32)outv[1]<<16);
  p[1] = (u32)outv[2] | ((u32)outv[3]<<16);
}

// ---------------- K5: q = hf @ wq^T + bq (BK=64, chunk-major) ----------------
__global__ __launch_bounds__(256) void k_qproj(const u16* __restrict__ hf, const u16* __restrict__ wqB,
    const float* __restrict__ bq, u16* __restrict__ qb){
  __shared__ u16 As[128*64];
  __shared__ u16 Bs[128*64];
  int bid = blockIdx.x;
  int nt = bid & 1, mt = bid >> 1;
  int co0 = nt*128;
  int tid = threadIdx.x;
  int w=tid>>6, lane=tid&63, ln=lane&15, qd=lane>>4, wm=w>>1, wn=w&1;
  f32x4 acc[4][4] = {};
  for(int s=0;s<4;s++){
    #pragma unroll
    for(int j=0;j<4;j++){
      int u = w*4 + j;
      int c = u>>1, half = u&1;
      int row = half*64 + lane;
      g2l16(hf  + ((size_t)(mt*128+row)*256 + s*64 + c*8), &As[u*512 + lane*8]);
      g2l16(wqB + ((size_t)(co0+row)*256 + s*64 + c*8),    &Bs[u*512 + lane*8]);
    }
    __syncthreads();
    #pragma unroll
    for(int kk=0;kk<2;kk++){
      bf16x8 af[4], bfv[4];
      #pragma unroll
      for(int mf=0;mf<4;mf++) af[mf]=ldfrag(&As[(kk*4+qd)*1024 + (wm*64+mf*16+ln)*8]);
      #pragma unroll
      for(int nf=0;nf<4;nf++) bfv[nf]=ldfrag(&Bs[(kk*4+qd)*1024 + (wn*64+nf*16+ln)*8]);
      #pragma unroll
      for(int mf=0;mf<4;mf++)
        #pragma unroll
        for(int nf=0;nf<4;nf++)
          acc[mf][nf]=__builtin_amdgcn_mfma_f32_16x16x32_bf16(af[mf],bfv[nf],acc[mf][nf],0,0,0);
    }
    __syncthreads();
  }
  for(int mf=0;mf<4;mf++) for(int nf=0;nf<4;nf++){
    int nl=wn*64+nf*16+ln; float bias=bq[co0+nl];
    for(int r=0;r<4;r++){
      int ml=wm*64+mf*16+qd*4+r;
      qb[((size_t)(mt*128+ml))*256 + co0+nl] = f2bf(acc[mf][nf][r]+bias);
    }
  }
}

// ---------------- K6: k,v = ctx @ {wk,wv}^T + b -> kb[b][77][256], vT[b][256][96] ----------
__global__ __launch_bounds__(256) void k_kvproj(const u16* __restrict__ ctxB, const u16* __restrict__ wkvB,
    const float* __restrict__ bk, const float* __restrict__ bv,
    u16* __restrict__ kb, u16* __restrict__ vT){
  __shared__ u16 As[128*32];
  __shared__ u16 Bs[128*32];
  int bid = blockIdx.x;
  int nt = bid & 3, mt = bid >> 2;
  int co0 = nt*128;
  int tid=threadIdx.x, w=tid>>6, lane=tid&63, ln=lane&15, qd=lane>>4, wm=w>>1, wn=w&1;
  int srow=tid>>2, koff=(tid&3)*8;
  f32x4 acc[4][4]={};
  for(int kt=0;kt<24;kt++){
    for(int j=0;j<2;j++){
      int m=srow+j*64;
      g2l16(ctxB + ((size_t)(mt*128+m)*768 + kt*32+koff), &As[(size_t)tid*8+j*2048]);
      g2l16(wkvB + ((size_t)(co0+m)*768 + kt*32+koff),    &Bs[(size_t)tid*8+j*2048]);
    }
    __syncthreads();
    bf16x8 af[4], bfv[4];
    for(int mf=0;mf<4;mf++) af[mf]=ldfrag(&As[(wm*64+mf*16+ln)*32+qd*8]);
    for(int nf=0;nf<4;nf++) bfv[nf]=ldfrag(&Bs[(wn*64+nf*16+ln)*32+qd*8]);
    for(int mf=0;mf<4;mf++) for(int nf=0;nf<4;nf++)
      acc[mf][nf]=__builtin_amdgcn_mfma_f32_16x16x32_bf16(af[mf],bfv[nf],acc[mf][nf],0,0,0);
    __syncthreads();
  }
  for(int mf=0;mf<4;mf++) for(int nf=0;nf<4;nf++){
    int nl=wn*64+nf*16+ln; int ng=co0+nl;
    float bias = ng<256 ? bk[ng] : bv[ng-256];
    for(int r=0;r<4;r++){
      int ml=wm*64+mf*16+qd*4+r; int mg=mt*128+ml;
      if(mg<1232){
        float v=acc[mf][nf][r]+bias;
        int bb=mg/77, l=mg-bb*77;
        if(ng<256) kb[((size_t)(bb*77+l))*256+ng]=f2bf(v);
        else vT[((size_t)(bb*256+(ng-256)))*96 + l]=f2bf(v);
      }
    }
  }
}

// ---------------- K7: attention per (b, 128-pixel q tile) ----------------
__global__ __launch_bounds__(256) void k_attn(const u16* __restrict__ qg, const u16* __restrict__ kb,
    const u16* __restrict__ vT, u16* __restrict__ ob){
  __shared__ u16 Qs[4096];        // 128 x 32
  __shared__ u16 KVs[4096];       // up to 128 x 32
  __shared__ u16 Sb[128*84];      // S scores, bf16, padded
  __shared__ u16 Pb[128*104];     // P, bf16, k-padded to 96 (+8)
  int bid=blockIdx.x; int b=bid>>5, qt=bid&31; int p0=qt*128;
  int tid=threadIdx.x, w=tid>>6, lane=tid&63, ln=lane&15, qd=lane>>4;
  int srow=tid>>2, koff=(tid&3)*8;
  f32x4 Sa[2][5]={};
  for(int kt=0;kt<8;kt++){
    for(int j=0;j<2;j++){
      int m=srow+j*64;
      g2l16(qg + ((size_t)(b*HW_+p0+m)*256 + kt*32+koff), &Qs[(size_t)tid*8+j*2048]);
    }
    for(int j=0;j<2;j++){
      int cja = tid + j*256;
      if(cja < 320){
        int l = cja>>2, ko2=(cja&3)*8;
        g2l16(kb + ((size_t)(b*77+l)*256 + kt*32+ko2), &KVs[(size_t)cja*8]);
      }
    }
    __syncthreads();
    bf16x8 af[2], bfv[5];
    for(int mf=0;mf<2;mf++) af[mf]=ldfrag(&Qs[(w*32+mf*16+ln)*32+qd*8]);
    for(int nf=0;nf<5;nf++) bfv[nf]=ldfrag(&KVs[(nf*16+ln)*32+qd*8]);
    for(int mf=0;mf<2;mf++) for(int nf=0;nf<5;nf++)
      Sa[mf][nf]=__builtin_amdgcn_mfma_f32_16x16x32_bf16(af[mf],bfv[nf],Sa[mf][nf],0,0,0);
    __syncthreads();
  }
  for(int mf=0;mf<2;mf++) for(int nf=0;nf<5;nf++) for(int r=0;r<4;r++){
    int ml=w*32+mf*16+qd*4+r, nl=nf*16+ln;
    Sb[ml*84+nl]=f2bf(Sa[mf][nf][r]*0.0625f);
  }
  __syncthreads();
  if(tid<128){
    const u16* srp = &Sb[tid*84];
    u16* prow = &Pb[tid*104];
    float mx=-1e30f;
    for(int j2=0;j2<77;j2++){ float v=bf2f(srp[j2]); mx=fmaxf(mx,v); }
    float sum=0.f;
    for(int j2=0;j2<77;j2++){ float e=__expf(bf2f(srp[j2])-mx); sum+=e; prow[j2]=f2bf(e); }
    float inv=1.f/sum;
    for(int j2=0;j2<77;j2++){ prow[j2]=f2bf(bf2f(prow[j2])*inv); }
    for(int j2=77;j2<104;j2++) prow[j2]=0;
  }
  __syncthreads();
  for(int nh=0;nh<2;nh++){
    f32x4 Oa[2][8]={};
    for(int kt2=0;kt2<3;kt2++){
      for(int j=0;j<2;j++){
        int chunk=tid+j*256;
        int co=chunk>>2, ko2=(chunk&3)*8;
        g2l16(vT + ((size_t)(b*256+nh*128+co)*96 + kt2*32+ko2), &KVs[(size_t)chunk*8]);
      }
      __syncthreads();
      bf16x8 af[2], bfv[8];
      for(int mf=0;mf<2;mf++) af[mf]=ldfrag(&Pb[(w*32+mf*16+ln)*104 + kt2*32+qd*8]);
      for(int nf=0;nf<8;nf++) bfv[nf]=ldfrag(&KVs[(nf*16+ln)*32+qd*8]);
      for(int mf=0;mf<2;mf++) for(int nf=0;nf<8;nf++)
        Oa[mf][nf]=__builtin_amdgcn_mfma_f32_16x16x32_bf16(af[mf],bfv[nf],Oa[mf][nf],0,0,0);
      __syncthreads();
    }
    for(int mf=0;mf<2;mf++) for(int nf=0;nf<8;nf++) for(int r=0;r<4;r++){
      int ml=w*32+mf*16+qd*4+r, nl=nh*128+nf*16+ln;
      ob[((size_t)(b*HW_+p0+ml))*256+nl]=f2bf(Oa[mf][nf][r]);
    }
  }
}

// ---------------- K8: out = x + (wo @ o^T) + bo, written NCHW (BK=64, chunk-major) -------
__global__ __launch_bounds__(256) void k_oproj(const u16* __restrict__ ob, const u16* __restrict__ woB,
    const float* __restrict__ bo, const float* __restrict__ x, float* __restrict__ outp){
  __shared__ u16 As[128*64];
  __shared__ u16 Bs[128*64];
  int bid=blockIdx.x;
  int b=bid>>6; int rr=bid&63; int cm=rr>>5, pt=rr&31;
  int c0=cm*128, p0=pt*128;
  int tid=threadIdx.x, w=tid>>6, lane=tid&63, ln=lane&15, qd=lane>>4, wm=w>>1, wn=w&1;
  f32x4 acc[4][4]={};
  for(int s=0;s<4;s++){
    #pragma unroll
    for(int j=0;j<4;j++){
      int u = w*4 + j;
      int c = u>>1, half = u&1;
      int row = half*64 + lane;
      g2l16(woB + ((size_t)(c0+row)*256 + s*64 + c*8),       &As[u*512 + lane*8]);
      g2l16(ob  + ((size_t)(b*HW_+p0+row)*256 + s*64 + c*8), &Bs[u*512 + lane*8]);
    }
    __syncthreads();
    #pragma unroll
    for(int kk=0;kk<2;kk++){
      bf16x8 af[4], bfv[4];
      #pragma unroll
      for(int mf=0;mf<4;mf++) af[mf]=ldfrag(&As[(kk*4+qd)*1024 + (wm*64+mf*16+ln)*8]);
      #pragma unroll
      for(int nf=0;nf<4;nf++) bfv[nf]=ldfrag(&Bs[(kk*4+qd)*1024 + (wn*64+nf*16+ln)*8]);
      #pragma unroll
      for(int mf=0;mf<4;mf++)
        #pragma unroll
        for(int nf=0;nf<4;nf++)
          acc[mf][nf]=__builtin_amdgcn_mfma_f32_16x16x32_bf16(af[mf],bfv[nf],acc[mf][nf],0,0,0);
    }
    __syncthreads();
  }
  for(int mf=0;mf<4;mf++) for(int r=0;r<4;r++){
    int cl=c0+wm*64+mf*16+qd*4+r;
    float bias=bo[cl];
    for(int nf=0;nf<4;nf++){
      int pl=p0+wn*64+nf*16+ln;
      size_t idx=((size_t)(b*C_+cl))*HW_+pl;
      outp[idx]=x[idx]+acc[mf][nf][r]+bias;
    }
  }
}

extern "C" void kernel_launch(void* const* d_in, const int* in_sizes, int n_in,
                              void* d_out, int out_size, void* d_ws, size_t ws_size,
                              hipStream_t stream){
  const float* x      = (const float*)d_in[0];
  const float* ctx    = (const float*)d_in[1];
  const float* conv_w = (const float*)d_in[2];
  const float* conv_b = (const float*)d_in[3];
  const float* gnw    = (const float*)d_in[4];
  const float* gnb    = (const float*)d_in[5];
  const float* wq     = (const float*)d_in[6];
  const float* bq     = (const float*)d_in[7];
  const float* wk     = (const float*)d_in[8];
  const float* bk     = (const float*)d_in[9];
  const float* wv     = (const float*)d_in[10];
  const float* bv     = (const float*)d_in[11];
  const float* wo     = (const float*)d_in[12];
  const float* bo     = (const float*)d_in[13];
  char* ws = (char*)d_ws;
  u16* xpT  = (u16*)(ws + 0);            // 35,684,352 ; reused as q after conv
  u16* wBt  = (u16*)(ws + 35684352);     //  1,179,648
  u16* wqB  = (u16*)(ws + 36864000);     //    131,072
  u16* wkvB = (u16*)(ws + 36995072);     //    786,432
  u16* woB  = (u16*)(ws + 37781504);     //    131,072
  u16* ctxB = (u16*)(ws + 37912576);     //  1,892,352
  u16* hbuf = (u16*)(ws + 39804928);     // 33,554,432 (h, then hf in place)
  u16* kbv  = (u16*)(ws + 73359360);     //    630,784
  u16* vT   = (u16*)(ws + 73990144);     //    786,432
  u16* obuf = (u16*)(ws + 74776576);     // 33,554,432
  float* stats = (float*)(ws + 108331008); // 2048
  u16* qb = xpT;
  float* outp = (float*)d_out;

  k_pad   <<<1056, 256, 0, stream>>>(x, xpT);
  k_repack<<<8050, 256, 0, stream>>>(conv_w, wq, wo, wk, wv, ctx, wBt, wqB, woB, wkvB, ctxB, stats);
  k_conv  <<<1024, 256, 0, stream>>>(xpT, wBt, conv_b, hbuf, stats);
  k_stats <<<1,    128, 0, stream>>>(stats);
  k_gnsilu<<<16384,256, 0, stream>>>(hbuf, stats, gnw, gnb);
  k_qproj <<<1024, 256, 0, stream>>>(hbuf, wqB, bq, qb);
  k_kvproj<<<40,   256, 0, stream>>>(ctxB, wkvB, bk, bv, kbv, vT);
  k_attn  <<<512,  256, 0, stream>>>(qb, kbv, vT, obuf);
  k_oproj <<<1024, 256, 0, stream>>>(obuf, woB, bo, x, outp);
}

// Round 3
// 574.028 us; speedup vs baseline: 1.0270x; 1.0270x over previous
//
#include <hip/hip_runtime.h>
#include <stdint.h>

#define B_  16
#define C_  256
#define HW_ 4096
#define Hp  66
#define PP  4356   // 66*66
#define EPS_ 1e-5f

typedef unsigned short u16;
typedef unsigned int   u32;
typedef __attribute__((ext_vector_type(4))) float  f32x4;
typedef __attribute__((ext_vector_type(8))) __bf16 bf16x8;
typedef __attribute__((ext_vector_type(8))) u16    u16x8;

__device__ __forceinline__ float bf2f(u16 u){ u32 x = ((u32)u)<<16; float f; __builtin_memcpy(&f,&x,4); return f; }
__device__ __forceinline__ u16 f2bf(float f){ u32 x; __builtin_memcpy(&x,&f,4); u32 r = x + 0x7fffu + ((x>>16)&1u); return (u16)(r>>16); }

__device__ __forceinline__ void g2l16(const void* g, void* l){
  __builtin_amdgcn_global_load_lds((__attribute__((address_space(1))) void*)(void*)g,
                                   (__attribute__((address_space(3))) void*)l, 16, 0, 0);
}
__device__ __forceinline__ bf16x8 ldfrag(const u16* p){
  u16x8 r = *(const u16x8*)p;
  return __builtin_bit_cast(bf16x8, r);
}

// ---------------- K0: pad + transpose + cast x -> xpT[b][66*66][256] bf16 ----------------
__global__ __launch_bounds__(256) void k_pad(const float* __restrict__ x, u16* __restrict__ xpT){
  int bid = blockIdx.x; int b = bid/66, hh = bid - b*66; int tid = threadIdx.x;
  u16* rowbase = xpT + (size_t)(b*PP + hh*Hp)*C_;
  if(hh==0 || hh==65){
    u32* p = (u32*)rowbase;
    for(int i=tid;i<66*C_/2;i+=256) p[i]=0u;
    return;
  }
  if(tid<128) ((u32*)rowbase)[tid]=0u;                 // ww = 0 border
  else ((u32*)(rowbase + 65*C_))[tid-128]=0u;          // ww = 65 border
  int h = hh-1;
  __shared__ float Lt[64*65];
  for(int cc=0; cc<4; cc++){
    int c0=cc*64;
    int ci = tid>>2, w0 = (tid&3)*16;
    const float* xs = x + ((size_t)(b*C_ + c0+ci)*HW_) + h*64 + w0;
    for(int j=0;j<4;j++){
      float4 v = *(const float4*)(xs + j*4);
      Lt[ci*65 + w0 + j*4 + 0] = v.x;
      Lt[ci*65 + w0 + j*4 + 1] = v.y;
      Lt[ci*65 + w0 + j*4 + 2] = v.z;
      Lt[ci*65 + w0 + j*4 + 3] = v.w;
    }
    __syncthreads();
    int w = tid>>2, cj = (tid&3)*16;
    union { u16 u[16]; uint4 v[2]; } outu;
    for(int j=0;j<16;j++) outu.u[j] = f2bf(Lt[(cj+j)*65 + w]);
    uint4* dst = (uint4*)(rowbase + (size_t)(w+1)*C_ + c0 + cj);
    dst[0]=outu.v[0]; dst[1]=outu.v[1];
    __syncthreads();
  }
}

// ---------------- K1: repack weights/context to bf16, zero stats ----------------
__global__ __launch_bounds__(256) void k_repack(
    const float* __restrict__ conv_w, const float* __restrict__ wq, const float* __restrict__ wo,
    const float* __restrict__ wk, const float* __restrict__ wv, const float* __restrict__ ctx,
    u16* __restrict__ wBt, u16* __restrict__ wqB, u16* __restrict__ woB,
    u16* __restrict__ wkvB, u16* __restrict__ ctxB, float* __restrict__ stats){
  int i = blockIdx.x*256 + threadIdx.x;
  if(i < 589824){ int co = i/2304, k = i - co*2304; int t = k>>8, ci = k&255;
    wBt[i] = f2bf(conv_w[(co*256+ci)*9 + t]); return; }
  i -= 589824;
  if(i < 65536){ wqB[i] = f2bf(wq[i]); return; } i -= 65536;
  if(i < 65536){ woB[i] = f2bf(wo[i]); return; } i -= 65536;
  if(i < 196608){ wkvB[i] = f2bf(wk[i]); return; } i -= 196608;
  if(i < 196608){ wkvB[196608+i] = f2bf(wv[i]); return; } i -= 196608;
  if(i < 946176){ ctxB[i] = f2bf(ctx[i]); return; } i -= 946176;
  if(i < 512){ stats[i] = 0.f; }
}

// ---------------- K2: conv implicit GEMM, BK=32, double-buffered single-barrier K-loop ----
// LDS layout: (row, kchunk c, e) -> rb*512 + rr*32 + c*8 + e   (rb=row>>4, rr=row&15)
// staging: lane rr*4+cc loads row rb*16+rr, k bytes cc*16 -> dest rb*512 + lane*8
// frag read: byte addr rb*1024 + ln*64 + qd*16 -> 64 lanes cover 1024 contiguous bytes
__global__ __launch_bounds__(256) void k_conv(const u16* __restrict__ xpT, const u16* __restrict__ wBt,
    const float* __restrict__ conv_b, u16* __restrict__ h, float* __restrict__ stats){
  __shared__ u16 As[2][4096];
  __shared__ u16 Bs[2][4096];
  int bid = blockIdx.x;
  int nt = bid & 1, mt = bid >> 1;
  int b = mt >> 5, hp = mt & 31;
  int co0 = nt*128;
  int tid = threadIdx.x;
  int w = tid>>6, lane = tid&63, ln = lane&15, qd = lane>>4;
  int wm = w>>1, wn = w&1;
  int rr = lane>>2, cc = lane&3;
  // per-thread staging constants for j=0,1
  int m0 = (w*2+0)*16 + rr, m1 = (w*2+1)*16 + rr;
  int wp0 = m0&63, hr0 = m0>>6, wp1 = m1&63, hr1 = m1>>6;
  const u16* Abase = xpT + (size_t)(b*PP + hp*2*Hp)*C_;
  f32x4 acc[4][4] = {};

  #define STAGE(kt, pb) { \
    int t_ = (kt)>>3, ci0_ = ((kt)&7)<<5; \
    int dy_ = (t_*11)>>5, dx_ = t_ - dy_*3; \
    g2l16(Abase + ((size_t)((hr0+dy_)*Hp + wp0 + dx_)*C_ + ci0_ + cc*8), &As[pb][(w*2+0)*512 + lane*8]); \
    g2l16(wBt + ((size_t)(co0+m0)*2304 + t_*256 + ci0_ + cc*8),          &Bs[pb][(w*2+0)*512 + lane*8]); \
    g2l16(Abase + ((size_t)((hr1+dy_)*Hp + wp1 + dx_)*C_ + ci0_ + cc*8), &As[pb][(w*2+1)*512 + lane*8]); \
    g2l16(wBt + ((size_t)(co0+m1)*2304 + t_*256 + ci0_ + cc*8),          &Bs[pb][(w*2+1)*512 + lane*8]); \
  }

  STAGE(0, 0);
  __syncthreads();
  for(int kt=0; kt<72; kt++){
    int cb = kt&1;
    if(kt<71) STAGE(kt+1, cb^1);
    bf16x8 af[4], bfv[4];
    #pragma unroll
    for(int mf=0;mf<4;mf++) af[mf] = ldfrag(&As[cb][(wm*4+mf)*512 + ln*32 + qd*8]);
    #pragma unroll
    for(int nf=0;nf<4;nf++) bfv[nf] = ldfrag(&Bs[cb][(wn*4+nf)*512 + ln*32 + qd*8]);
    #pragma unroll
    for(int mf=0;mf<4;mf++)
      #pragma unroll
      for(int nf=0;nf<4;nf++)
        acc[mf][nf] = __builtin_amdgcn_mfma_f32_16x16x32_bf16(af[mf], bfv[nf], acc[mf][nf], 0,0,0);
    __syncthreads();
  }
  #undef STAGE

  float s0=0.f,q0=0.f,s1=0.f,q1=0.f;
  int p0 = hp*128;
  for(int mf=0;mf<4;mf++) for(int nf=0;nf<4;nf++){
    int nl = wn*64 + nf*16 + ln;
    float bias = conv_b[co0+nl];
    for(int r=0;r<4;r++){
      int ml = wm*64 + mf*16 + qd*4 + r;
      float v = acc[mf][nf][r] + bias;
      h[((size_t)(b*HW_ + p0 + ml))*C_ + co0 + nl] = f2bf(v);
      if(nf<2){ s0+=v; q0+=v*v; } else { s1+=v; q1+=v*v; }
    }
  }
  for(int off=32;off>=1;off>>=1){
    s0 += __shfl_down(s0,off,64); q0 += __shfl_down(q0,off,64);
    s1 += __shfl_down(s1,off,64); q1 += __shfl_down(q1,off,64);
  }
  if(lane==0){
    int g0 = (co0 + wn*64)>>5;
    atomicAdd(&stats[(b*8+g0)*2+0], s0);
    atomicAdd(&stats[(b*8+g0)*2+1], q0);
    atomicAdd(&stats[(b*8+g0+1)*2+0], s1);
    atomicAdd(&stats[(b*8+g0+1)*2+1], q1);
  }
}

// ---------------- K3: finalize GN stats ----------------
__global__ void k_stats(float* __restrict__ stats){
  int t = threadIdx.x;
  if(t<128){
    float s = stats[t*2], q = stats[t*2+1];
    float inv = 1.f/131072.f;
    float mean = s*inv;
    float var = q*inv - mean*mean;
    stats[256 + t*2]   = mean;
    stats[256 + t*2+1] = rsqrtf(var + EPS_);
  }
}

// ---------------- K4: GN + SiLU, in place on h ----------------
__global__ __launch_bounds__(256) void k_gnsilu(u16* __restrict__ hbuf, const float* __restrict__ stats,
      const float* __restrict__ gnw, const float* __restrict__ gnb){
  size_t i = ((size_t)blockIdx.x*256 + threadIdx.x)*4;
  int c0 = (int)(i & 255);
  size_t row = i >> 8;
  int b = (int)(row >> 12);
  int g = c0 >> 5;
  float mean = stats[256 + (b*8+g)*2];
  float rstd = stats[256 + (b*8+g)*2+1];
  u32* p = (u32*)(hbuf + i);
  u32 v0 = p[0], v1 = p[1];
  u16 in[4] = {(u16)(v0&0xffff),(u16)(v0>>16),(u16)(v1&0xffff),(u16)(v1>>16)};
  u16 outv[4];
  for(int j=0;j<4;j++){
    float v = bf2f(in[j]);
    v = (v-mean)*rstd*gnw[c0+j] + gnb[c0+j];
    float s = v/(1.f+__expf(-v));
    outv[j] = f2bf(s);
  }
  p[0] = (u32)outv[0] | ((u32)outv[1]<<16);
  p[1] = (u32)outv[2] | ((u32)outv[3]<<16);
}

// ---------------- K5: q = hf @ wq^T + bq (BK=32, dbuf) ----------------
__global__ __launch_bounds__(256) void k_qproj(const u16* __restrict__ hf, const u16* __restrict__ wqB,
    const float* __restrict__ bq, u16* __restrict__ qb){
  __shared__ u16 As[2][4096];
  __shared__ u16 Bs[2][4096];
  int bid = blockIdx.x;
  int nt = bid & 1, mt = bid >> 1;
  int co0 = nt*128;
  int tid = threadIdx.x;
  int w=tid>>6, lane=tid&63, ln=lane&15, qd=lane>>4, wm=w>>1, wn=w&1;
  int rr = lane>>2, cc = lane&3;
  int m0 = (w*2+0)*16 + rr, m1 = (w*2+1)*16 + rr;
  const u16* Ar0 = hf + ((size_t)(mt*128+m0)*256) + cc*8;
  const u16* Ar1 = hf + ((size_t)(mt*128+m1)*256) + cc*8;
  const u16* Br0 = wqB + ((size_t)(co0+m0)*256) + cc*8;
  const u16* Br1 = wqB + ((size_t)(co0+m1)*256) + cc*8;
  f32x4 acc[4][4] = {};
  #define STAGE(kt, pb) { \
    g2l16(Ar0 + (kt)*32, &As[pb][(w*2+0)*512 + lane*8]); \
    g2l16(Br0 + (kt)*32, &Bs[pb][(w*2+0)*512 + lane*8]); \
    g2l16(Ar1 + (kt)*32, &As[pb][(w*2+1)*512 + lane*8]); \
    g2l16(Br1 + (kt)*32, &Bs[pb][(w*2+1)*512 + lane*8]); \
  }
  STAGE(0, 0);
  __syncthreads();
  for(int kt=0;kt<8;kt++){
    int cb = kt&1;
    if(kt<7) STAGE(kt+1, cb^1);
    bf16x8 af[4], bfv[4];
    #pragma unroll
    for(int mf=0;mf<4;mf++) af[mf]=ldfrag(&As[cb][(wm*4+mf)*512 + ln*32 + qd*8]);
    #pragma unroll
    for(int nf=0;nf<4;nf++) bfv[nf]=ldfrag(&Bs[cb][(wn*4+nf)*512 + ln*32 + qd*8]);
    #pragma unroll
    for(int mf=0;mf<4;mf++)
      #pragma unroll
      for(int nf=0;nf<4;nf++)
        acc[mf][nf]=__builtin_amdgcn_mfma_f32_16x16x32_bf16(af[mf],bfv[nf],acc[mf][nf],0,0,0);
    __syncthreads();
  }
  #undef STAGE
  for(int mf=0;mf<4;mf++) for(int nf=0;nf<4;nf++){
    int nl=wn*64+nf*16+ln; float bias=bq[co0+nl];
    for(int r=0;r<4;r++){
      int ml=wm*64+mf*16+qd*4+r;
      qb[((size_t)(mt*128+ml))*256 + co0+nl] = f2bf(acc[mf][nf][r]+bias);
    }
  }
}

// ---------------- K6: k,v = ctx @ {wk,wv}^T + b -> kb[b][77][256], vT[b][256][96] ----------
__global__ __launch_bounds__(256) void k_kvproj(const u16* __restrict__ ctxB, const u16* __restrict__ wkvB,
    const float* __restrict__ bk, const float* __restrict__ bv,
    u16* __restrict__ kb, u16* __restrict__ vT){
  __shared__ u16 As[128*32];
  __shared__ u16 Bs[128*32];
  int bid = blockIdx.x;
  int nt = bid & 3, mt = bid >> 2;
  int co0 = nt*128;
  int tid=threadIdx.x, w=tid>>6, lane=tid&63, ln=lane&15, qd=lane>>4, wm=w>>1, wn=w&1;
  int srow=tid>>2, koff=(tid&3)*8;
  f32x4 acc[4][4]={};
  for(int kt=0;kt<24;kt++){
    for(int j=0;j<2;j++){
      int m=srow+j*64;
      g2l16(ctxB + ((size_t)(mt*128+m)*768 + kt*32+koff), &As[(size_t)tid*8+j*2048]);
      g2l16(wkvB + ((size_t)(co0+m)*768 + kt*32+koff),    &Bs[(size_t)tid*8+j*2048]);
    }
    __syncthreads();
    bf16x8 af[4], bfv[4];
    for(int mf=0;mf<4;mf++) af[mf]=ldfrag(&As[(wm*64+mf*16+ln)*32+qd*8]);
    for(int nf=0;nf<4;nf++) bfv[nf]=ldfrag(&Bs[(wn*64+nf*16+ln)*32+qd*8]);
    for(int mf=0;mf<4;mf++) for(int nf=0;nf<4;nf++)
      acc[mf][nf]=__builtin_amdgcn_mfma_f32_16x16x32_bf16(af[mf],bfv[nf],acc[mf][nf],0,0,0);
    __syncthreads();
  }
  for(int mf=0;mf<4;mf++) for(int nf=0;nf<4;nf++){
    int nl=wn*64+nf*16+ln; int ng=co0+nl;
    float bias = ng<256 ? bk[ng] : bv[ng-256];
    for(int r=0;r<4;r++){
      int ml=wm*64+mf*16+qd*4+r; int mg=mt*128+ml;
      if(mg<1232){
        float v=acc[mf][nf][r]+bias;
        int bb=mg/77, l=mg-bb*77;
        if(ng<256) kb[((size_t)(bb*77+l))*256+ng]=f2bf(v);
        else vT[((size_t)(bb*256+(ng-256)))*96 + l]=f2bf(v);
      }
    }
  }
}

// ---------------- K7: attention per (b, 128-pixel q tile) ----------------
__global__ __launch_bounds__(256) void k_attn(const u16* __restrict__ qg, const u16* __restrict__ kb,
    const u16* __restrict__ vT, u16* __restrict__ ob){
  __shared__ u16 Qs[4096];        // 128 x 32
  __shared__ u16 KVs[4096];       // up to 128 x 32
  __shared__ u16 Sb[128*84];      // S scores, bf16, padded
  __shared__ u16 Pb[128*104];     // P, bf16, k-padded to 96 (+8)
  int bid=blockIdx.x; int b=bid>>5, qt=bid&31; int p0=qt*128;
  int tid=threadIdx.x, w=tid>>6, lane=tid&63, ln=lane&15, qd=lane>>4;
  int srow=tid>>2, koff=(tid&3)*8;
  f32x4 Sa[2][5]={};
  for(int kt=0;kt<8;kt++){
    for(int j=0;j<2;j++){
      int m=srow+j*64;
      g2l16(qg + ((size_t)(b*HW_+p0+m)*256 + kt*32+koff), &Qs[(size_t)tid*8+j*2048]);
    }
    for(int j=0;j<2;j++){
      int cja = tid + j*256;
      if(cja < 320){
        int l = cja>>2, ko2=(cja&3)*8;
        g2l16(kb + ((size_t)(b*77+l)*256 + kt*32+ko2), &KVs[(size_t)cja*8]);
      }
    }
    __syncthreads();
    bf16x8 af[2], bfv[5];
    for(int mf=0;mf<2;mf++) af[mf]=ldfrag(&Qs[(w*32+mf*16+ln)*32+qd*8]);
    for(int nf=0;nf<5;nf++) bfv[nf]=ldfrag(&KVs[(nf*16+ln)*32+qd*8]);
    for(int mf=0;mf<2;mf++) for(int nf=0;nf<5;nf++)
      Sa[mf][nf]=__builtin_amdgcn_mfma_f32_16x16x32_bf16(af[mf],bfv[nf],Sa[mf][nf],0,0,0);
    __syncthreads();
  }
  for(int mf=0;mf<2;mf++) for(int nf=0;nf<5;nf++) for(int r=0;r<4;r++){
    int ml=w*32+mf*16+qd*4+r, nl=nf*16+ln;
    Sb[ml*84+nl]=f2bf(Sa[mf][nf][r]*0.0625f);
  }
  __syncthreads();
  if(tid<128){
    const u16* srp = &Sb[tid*84];
    u16* prow = &Pb[tid*104];
    float mx=-1e30f;
    for(int j2=0;j2<77;j2++){ float v=bf2f(srp[j2]); mx=fmaxf(mx,v); }
    float sum=0.f;
    for(int j2=0;j2<77;j2++){ float e=__expf(bf2f(srp[j2])-mx); sum+=e; prow[j2]=f2bf(e); }
    float inv=1.f/sum;
    for(int j2=0;j2<77;j2++){ prow[j2]=f2bf(bf2f(prow[j2])*inv); }
    for(int j2=77;j2<104;j2++) prow[j2]=0;
  }
  __syncthreads();
  for(int nh=0;nh<2;nh++){
    f32x4 Oa[2][8]={};
    for(int kt2=0;kt2<3;kt2++){
      for(int j=0;j<2;j++){
        int chunk=tid+j*256;
        int co=chunk>>2, ko2=(chunk&3)*8;
        g2l16(vT + ((size_t)(b*256+nh*128+co)*96 + kt2*32+ko2), &KVs[(size_t)chunk*8]);
      }
      __syncthreads();
      bf16x8 af[2], bfv[8];
      for(int mf=0;mf<2;mf++) af[mf]=ldfrag(&Pb[(w*32+mf*16+ln)*104 + kt2*32+qd*8]);
      for(int nf=0;nf<8;nf++) bfv[nf]=ldfrag(&KVs[(nf*16+ln)*32+qd*8]);
      for(int mf=0;mf<2;mf++) for(int nf=0;nf<8;nf++)
        Oa[mf][nf]=__builtin_amdgcn_mfma_f32_16x16x32_bf16(af[mf],bfv[nf],Oa[mf][nf],0,0,0);
      __syncthreads();
    }
    for(int mf=0;mf<2;mf++) for(int nf=0;nf<8;nf++) for(int r=0;r<4;r++){
      int ml=w*32+mf*16+qd*4+r, nl=nh*128+nf*16+ln;
      ob[((size_t)(b*HW_+p0+ml))*256+nl]=f2bf(Oa[mf][nf][r]);
    }
  }
}

// ---------------- K8: out = x + (wo @ o^T) + bo, written NCHW (BK=32, dbuf) -------
__global__ __launch_bounds__(256) void k_oproj(const u16* __restrict__ ob, const u16* __restrict__ woB,
    const float* __restrict__ bo, const float* __restrict__ x, float* __restrict__ outp){
  __shared__ u16 As[2][4096];
  __shared__ u16 Bs[2][4096];
  int bid=blockIdx.x;
  int b=bid>>6; int rr2=bid&63; int cm=rr2>>5, pt=rr2&31;
  int c0=cm*128, p0=pt*128;
  int tid=threadIdx.x, w=tid>>6, lane=tid&63, ln=lane&15, qd=lane>>4, wm=w>>1, wn=w&1;
  int rr = lane>>2, cc = lane&3;
  int m0 = (w*2+0)*16 + rr, m1 = (w*2+1)*16 + rr;
  const u16* Ar0 = woB + ((size_t)(c0+m0)*256) + cc*8;
  const u16* Ar1 = woB + ((size_t)(c0+m1)*256) + cc*8;
  const u16* Br0 = ob + ((size_t)(b*HW_+p0+m0)*256) + cc*8;
  const u16* Br1 = ob + ((size_t)(b*HW_+p0+m1)*256) + cc*8;
  f32x4 acc[4][4]={};
  #define STAGE(kt, pb) { \
    g2l16(Ar0 + (kt)*32, &As[pb][(w*2+0)*512 + lane*8]); \
    g2l16(Br0 + (kt)*32, &Bs[pb][(w*2+0)*512 + lane*8]); \
    g2l16(Ar1 + (kt)*32, &As[pb][(w*2+1)*512 + lane*8]); \
    g2l16(Br1 + (kt)*32, &Bs[pb][(w*2+1)*512 + lane*8]); \
  }
  STAGE(0, 0);
  __syncthreads();
  for(int kt=0;kt<8;kt++){
    int cb = kt&1;
    if(kt<7) STAGE(kt+1, cb^1);
    bf16x8 af[4], bfv[4];
    #pragma unroll
    for(int mf=0;mf<4;mf++) af[mf]=ldfrag(&As[cb][(wm*4+mf)*512 + ln*32 + qd*8]);
    #pragma unroll
    for(int nf=0;nf<4;nf++) bfv[nf]=ldfrag(&Bs[cb][(wn*4+nf)*512 + ln*32 + qd*8]);
    #pragma unroll
    for(int mf=0;mf<4;mf++)
      #pragma unroll
      for(int nf=0;nf<4;nf++)
        acc[mf][nf]=__builtin_amdgcn_mfma_f32_16x16x32_bf16(af[mf],bfv[nf],acc[mf][nf],0,0,0);
    __syncthreads();
  }
  #undef STAGE
  for(int mf=0;mf<4;mf++) for(int r=0;r<4;r++){
    int cl=c0+wm*64+mf*16+qd*4+r;
    float bias=bo[cl];
    for(int nf=0;nf<4;nf++){
      int pl=p0+wn*64+nf*16+ln;
      size_t idx=((size_t)(b*C_+cl))*HW_+pl;
      outp[idx]=x[idx]+acc[mf][nf][r]+bias;
    }
  }
}

extern "C" void kernel_launch(void* const* d_in, const int* in_sizes, int n_in,
                              void* d_out, int out_size, void* d_ws, size_t ws_size,
                              hipStream_t stream){
  const float* x      = (const float*)d_in[0];
  const float* ctx    = (const float*)d_in[1];
  const float* conv_w = (const float*)d_in[2];
  const float* conv_b = (const float*)d_in[3];
  const float* gnw    = (const float*)d_in[4];
  const float* gnb    = (const float*)d_in[5];
  const float* wq     = (const float*)d_in[6];
  const float* bq     = (const float*)d_in[7];
  const float* wk     = (const float*)d_in[8];
  const float* bk     = (const float*)d_in[9];
  const float* wv     = (const float*)d_in[10];
  const float* bv     = (const float*)d_in[11];
  const float* wo     = (const float*)d_in[12];
  const float* bo     = (const float*)d_in[13];
  char* ws = (char*)d_ws;
  u16* xpT  = (u16*)(ws + 0);            // 35,684,352 ; reused as q after conv
  u16* wBt  = (u16*)(ws + 35684352);     //  1,179,648
  u16* wqB  = (u16*)(ws + 36864000);     //    131,072
  u16* wkvB = (u16*)(ws + 36995072);     //    786,432
  u16* woB  = (u16*)(ws + 37781504);     //    131,072
  u16* ctxB = (u16*)(ws + 37912576);     //  1,892,352
  u16* hbuf = (u16*)(ws + 39804928);     // 33,554,432 (h, then hf in place)
  u16* kbv  = (u16*)(ws + 73359360);     //    630,784
  u16* vT   = (u16*)(ws + 73990144);     //    786,432
  u16* obuf = (u16*)(ws + 74776576);     // 33,554,432
  float* stats = (float*)(ws + 108331008); // 2048
  u16* qb = xpT;
  float* outp = (float*)d_out;

  k_pad   <<<1056, 256, 0, stream>>>(x, xpT);
  k_repack<<<8050, 256, 0, stream>>>(conv_w, wq, wo, wk, wv, ctx, wBt, wqB, woB, wkvB, ctxB, stats);
  k_conv  <<<1024, 256, 0, stream>>>(xpT, wBt, conv_b, hbuf, stats);
  k_stats <<<1,    128, 0, stream>>>(stats);
  k_gnsilu<<<16384,256, 0, stream>>>(hbuf, stats, gnw, gnb);
  k_qproj <<<1024, 256, 0, stream>>>(hbuf, wqB, bq, qb);
  k_kvproj<<<40,   256, 0, stream>>>(ctxB, wkvB, bk, bv, kbv, vT);
  k_attn  <<<512,  256, 0, stream>>>(qb, kbv, vT, obuf);
  k_oproj <<<1024, 256, 0, stream>>>(obuf, woB, bo, x, outp);
}

// Round 4
// 490.971 us; speedup vs baseline: 1.2008x; 1.1692x over previous
//
#include <hip/hip_runtime.h>
#include <stdint.h>

#define B_  16
#define C_  256
#define HW_ 4096
#define Hp  66
#define PP  4356   // 66*66
#define EPS_ 1e-5f

typedef unsigned short u16;
typedef unsigned int   u32;
typedef __attribute__((ext_vector_type(4))) float  f32x4;
typedef __attribute__((ext_vector_type(8))) __bf16 bf16x8;
typedef __attribute__((ext_vector_type(8))) u16    u16x8;

__device__ __forceinline__ float bf2f(u16 u){ u32 x = ((u32)u)<<16; float f; __builtin_memcpy(&f,&x,4); return f; }
__device__ __forceinline__ u16 f2bf(float f){ u32 x; __builtin_memcpy(&x,&f,4); u32 r = x + 0x7fffu + ((x>>16)&1u); return (u16)(r>>16); }

__device__ __forceinline__ void g2l16(const void* g, void* l){
  __builtin_amdgcn_global_load_lds((__attribute__((address_space(1))) void*)(void*)g,
                                   (__attribute__((address_space(3))) void*)l, 16, 0, 0);
}
__device__ __forceinline__ bf16x8 ldfrag(const u16* p){
  u16x8 r = *(const u16x8*)p;
  return __builtin_bit_cast(bf16x8, r);
}

// ---------------- K0: pad + transpose + cast x -> xpT[b][66*66][256] bf16 ----------------
__global__ __launch_bounds__(256) void k_pad(const float* __restrict__ x, u16* __restrict__ xpT){
  int bid = blockIdx.x; int b = bid/66, hh = bid - b*66; int tid = threadIdx.x;
  u16* rowbase = xpT + (size_t)(b*PP + hh*Hp)*C_;
  if(hh==0 || hh==65){
    u32* p = (u32*)rowbase;
    for(int i=tid;i<66*C_/2;i+=256) p[i]=0u;
    return;
  }
  if(tid<128) ((u32*)rowbase)[tid]=0u;                 // ww = 0 border
  else ((u32*)(rowbase + 65*C_))[tid-128]=0u;          // ww = 65 border
  int h = hh-1;
  __shared__ float Lt[64*65];
  for(int cc=0; cc<4; cc++){
    int c0=cc*64;
    int ci = tid>>2, w0 = (tid&3)*16;
    const float* xs = x + ((size_t)(b*C_ + c0+ci)*HW_) + h*64 + w0;
    for(int j=0;j<4;j++){
      float4 v = *(const float4*)(xs + j*4);
      Lt[ci*65 + w0 + j*4 + 0] = v.x;
      Lt[ci*65 + w0 + j*4 + 1] = v.y;
      Lt[ci*65 + w0 + j*4 + 2] = v.z;
      Lt[ci*65 + w0 + j*4 + 3] = v.w;
    }
    __syncthreads();
    int w = tid>>2, cj = (tid&3)*16;
    union { u16 u[16]; uint4 v[2]; } outu;
    for(int j=0;j<16;j++) outu.u[j] = f2bf(Lt[(cj+j)*65 + w]);
    uint4* dst = (uint4*)(rowbase + (size_t)(w+1)*C_ + c0 + cj);
    dst[0]=outu.v[0]; dst[1]=outu.v[1];
    __syncthreads();
  }
}

// ---------------- K1: repack weights/context to bf16, zero stats ----------------
__global__ __launch_bounds__(256) void k_repack(
    const float* __restrict__ conv_w, const float* __restrict__ wq, const float* __restrict__ wo,
    const float* __restrict__ wk, const float* __restrict__ wv, const float* __restrict__ ctx,
    u16* __restrict__ wBt, u16* __restrict__ wqB, u16* __restrict__ woB,
    u16* __restrict__ wkvB, u16* __restrict__ ctxB, float* __restrict__ stats){
  int i = blockIdx.x*256 + threadIdx.x;
  if(i < 589824){ int co = i/2304, k = i - co*2304; int t = k>>8, ci = k&255;
    wBt[i] = f2bf(conv_w[(co*256+ci)*9 + t]); return; }
  i -= 589824;
  if(i < 65536){ wqB[i] = f2bf(wq[i]); return; } i -= 65536;
  if(i < 65536){ woB[i] = f2bf(wo[i]); return; } i -= 65536;
  if(i < 196608){ wkvB[i] = f2bf(wk[i]); return; } i -= 196608;
  if(i < 196608){ wkvB[196608+i] = f2bf(wv[i]); return; } i -= 196608;
  if(i < 946176){ ctxB[i] = f2bf(ctx[i]); return; } i -= 946176;
  if(i < 512){ stats[i] = 0.f; }
}

// ---------------- K2: conv implicit GEMM, A-slab resident across taps ----------------
// Tile: 128 px x 256 co. Outer: 8 ci-chunks of 32. A-slab = 264 contiguous xpT rows x 32ci
// staged ONCE per ci-chunk; inner 9 taps stage only B (256co x 32ci, L2-hot).
// LDS: As 16896 B + Bs 16384 B = 33280 B -> 2 blocks/CU (grid 512 = 2/CU).
__global__ __launch_bounds__(256, 2) void k_conv(const u16* __restrict__ xpT, const u16* __restrict__ wBt,
    const float* __restrict__ conv_b, u16* __restrict__ h, float* __restrict__ stats){
  __shared__ u16 As[264*32];
  __shared__ u16 Bs[256*32];
  int bid = blockIdx.x;
  int b = bid >> 5, hp = bid & 31;
  int tid = threadIdx.x;
  int w = tid>>6, lane = tid&63, ln = lane&15, qd = lane>>4;
  int wm = w&1, wn = w>>1;
  const u16* Abase = xpT + (size_t)(b*PP + hp*132)*C_;
  f32x4 acc[4][8] = {};
  // per-lane A-frag pixel components (tap-independent)
  int hr_[4], wp_[4];
  #pragma unroll
  for(int mf=0;mf<4;mf++){ int p = wm*64 + mf*16 + ln; hr_[mf] = p>>6; wp_[mf] = p&63; }

  for(int ci=0; ci<8; ci++){
    int ci0 = ci*32;
    // stage A slab: 264 rows x 4 atoms = 1056 16B-chunks
    #pragma unroll
    for(int r=0;r<5;r++){
      int c = r*256 + tid;
      if(c < 1056){
        int ipix = c>>2, atom = c&3;
        g2l16(Abase + (size_t)ipix*C_ + ci0 + atom*8, &As[c*8]);
      }
    }
    for(int t=0;t<9;t++){
      int dy = (t*11)>>5, dx = t - dy*3;
      // stage B tile: 256 co x 32 ci
      #pragma unroll
      for(int r=0;r<4;r++){
        int c = r*256 + tid;
        int co = c>>2, atom = c&3;
        g2l16(wBt + (size_t)co*2304 + t*256 + ci0 + atom*8, &Bs[c*8]);
      }
      __syncthreads();
      bf16x8 af[4], bfv[8];
      #pragma unroll
      for(int mf=0;mf<4;mf++){
        int ipix = (hr_[mf]+dy)*66 + wp_[mf] + dx;
        af[mf] = ldfrag(&As[ipix*32 + qd*8]);
      }
      #pragma unroll
      for(int nf=0;nf<8;nf++) bfv[nf] = ldfrag(&Bs[(wn*128+nf*16+ln)*32 + qd*8]);
      #pragma unroll
      for(int mf=0;mf<4;mf++)
        #pragma unroll
        for(int nf=0;nf<8;nf++)
          acc[mf][nf] = __builtin_amdgcn_mfma_f32_16x16x32_bf16(af[mf], bfv[nf], acc[mf][nf], 0,0,0);
      __syncthreads();
    }
  }
  // epilogue: bias, h-write, GN partial stats (8 groups; this wave touches groups wn*4..wn*4+3)
  float s[4]={0,0,0,0}, q[4]={0,0,0,0};
  int p0 = hp*128;
  for(int nf=0;nf<8;nf++){
    int n = wn*128 + nf*16 + ln;
    float bias = conv_b[n];
    for(int mf=0;mf<4;mf++){
      for(int r=0;r<4;r++){
        int p = wm*64 + mf*16 + qd*4 + r;
        float v = acc[mf][nf][r] + bias;
        h[((size_t)(b*HW_ + p0 + p))*C_ + n] = f2bf(v);
        s[nf>>1]+=v; q[nf>>1]+=v*v;
      }
    }
  }
  for(int off=32;off>=1;off>>=1){
    #pragma unroll
    for(int g=0;g<4;g++){ s[g]+=__shfl_down(s[g],off,64); q[g]+=__shfl_down(q[g],off,64); }
  }
  if(lane==0){
    #pragma unroll
    for(int g=0;g<4;g++){
      atomicAdd(&stats[(b*8 + wn*4 + g)*2+0], s[g]);
      atomicAdd(&stats[(b*8 + wn*4 + g)*2+1], q[g]);
    }
  }
}

// ---------------- K3: finalize GN stats ----------------
__global__ void k_stats(float* __restrict__ stats){
  int t = threadIdx.x;
  if(t<128){
    float s = stats[t*2], q = stats[t*2+1];
    float inv = 1.f/131072.f;
    float mean = s*inv;
    float var = q*inv - mean*mean;
    stats[256 + t*2]   = mean;
    stats[256 + t*2+1] = rsqrtf(var + EPS_);
  }
}

// ---------------- K4: GN + SiLU, in place on h ----------------
__global__ __launch_bounds__(256) void k_gnsilu(u16* __restrict__ hbuf, const float* __restrict__ stats,
      const float* __restrict__ gnw, const float* __restrict__ gnb){
  size_t i = ((size_t)blockIdx.x*256 + threadIdx.x)*4;
  int c0 = (int)(i & 255);
  size_t row = i >> 8;
  int b = (int)(row >> 12);
  int g = c0 >> 5;
  float mean = stats[256 + (b*8+g)*2];
  float rstd = stats[256 + (b*8+g)*2+1];
  u32* p = (u32*)(hbuf + i);
  u32 v0 = p[0], v1 = p[1];
  u16 in[4] = {(u16)(v0&0xffff),(u16)(v0>>16),(u16)(v1&0xffff),(u16)(v1>>16)};
  u16 outv[4];
  for(int j=0;j<4;j++){
    float v = bf2f(in[j]);
    v = (v-mean)*rstd*gnw[c0+j] + gnb[c0+j];
    float s = v/(1.f+__expf(-v));
    outv[j] = f2bf(s);
  }
  p[0] = (u32)outv[0] | ((u32)outv[1]<<16);
  p[1] = (u32)outv[2] | ((u32)outv[3]<<16);
}

// ---------------- K5: q = hf @ wq^T + bq (round-1 structure) ----------------
__global__ __launch_bounds__(256) void k_qproj(const u16* __restrict__ hf, const u16* __restrict__ wqB,
    const float* __restrict__ bq, u16* __restrict__ qb){
  __shared__ u16 As[128*32];
  __shared__ u16 Bs[128*32];
  int bid = blockIdx.x;
  int nt = bid & 1, mt = bid >> 1;
  int co0 = nt*128;
  int tid = threadIdx.x;
  int w=tid>>6, lane=tid&63, ln=lane&15, qd=lane>>4, wm=w>>1, wn=w&1;
  int srow=tid>>2, koff=(tid&3)*8;
  f32x4 acc[4][4] = {};
  for(int kt=0;kt<8;kt++){
    for(int j=0;j<2;j++){
      int m = srow + j*64;
      g2l16(hf  + ((size_t)(mt*128+m)*256 + kt*32 + koff), &As[(size_t)tid*8 + j*2048]);
      g2l16(wqB + ((size_t)(co0+m)*256 + kt*32 + koff),    &Bs[(size_t)tid*8 + j*2048]);
    }
    __syncthreads();
    bf16x8 af[4], bfv[4];
    for(int mf=0;mf<4;mf++) af[mf]=ldfrag(&As[(wm*64+mf*16+ln)*32+qd*8]);
    for(int nf=0;nf<4;nf++) bfv[nf]=ldfrag(&Bs[(wn*64+nf*16+ln)*32+qd*8]);
    for(int mf=0;mf<4;mf++) for(int nf=0;nf<4;nf++)
      acc[mf][nf]=__builtin_amdgcn_mfma_f32_16x16x32_bf16(af[mf],bfv[nf],acc[mf][nf],0,0,0);
    __syncthreads();
  }
  for(int mf=0;mf<4;mf++) for(int nf=0;nf<4;nf++){
    int nl=wn*64+nf*16+ln; float bias=bq[co0+nl];
    for(int r=0;r<4;r++){
      int ml=wm*64+mf*16+qd*4+r;
      qb[((size_t)(mt*128+ml))*256 + co0+nl] = f2bf(acc[mf][nf][r]+bias);
    }
  }
}

// ---------------- K6: k,v = ctx @ {wk,wv}^T + b -> kb[b][77][256], vT[b][256][96] ----------
__global__ __launch_bounds__(256) void k_kvproj(const u16* __restrict__ ctxB, const u16* __restrict__ wkvB,
    const float* __restrict__ bk, const float* __restrict__ bv,
    u16* __restrict__ kb, u16* __restrict__ vT){
  __shared__ u16 As[128*32];
  __shared__ u16 Bs[128*32];
  int bid = blockIdx.x;
  int nt = bid & 3, mt = bid >> 2;
  int co0 = nt*128;
  int tid=threadIdx.x, w=tid>>6, lane=tid&63, ln=lane&15, qd=lane>>4, wm=w>>1, wn=w&1;
  int srow=tid>>2, koff=(tid&3)*8;
  f32x4 acc[4][4]={};
  for(int kt=0;kt<24;kt++){
    for(int j=0;j<2;j++){
      int m=srow+j*64;
      g2l16(ctxB + ((size_t)(mt*128+m)*768 + kt*32+koff), &As[(size_t)tid*8+j*2048]);
      g2l16(wkvB + ((size_t)(co0+m)*768 + kt*32+koff),    &Bs[(size_t)tid*8+j*2048]);
    }
    __syncthreads();
    bf16x8 af[4], bfv[4];
    for(int mf=0;mf<4;mf++) af[mf]=ldfrag(&As[(wm*64+mf*16+ln)*32+qd*8]);
    for(int nf=0;nf<4;nf++) bfv[nf]=ldfrag(&Bs[(wn*64+nf*16+ln)*32+qd*8]);
    for(int mf=0;mf<4;mf++) for(int nf=0;nf<4;nf++)
      acc[mf][nf]=__builtin_amdgcn_mfma_f32_16x16x32_bf16(af[mf],bfv[nf],acc[mf][nf],0,0,0);
    __syncthreads();
  }
  for(int mf=0;mf<4;mf++) for(int nf=0;nf<4;nf++){
    int nl=wn*64+nf*16+ln; int ng=co0+nl;
    float bias = ng<256 ? bk[ng] : bv[ng-256];
    for(int r=0;r<4;r++){
      int ml=wm*64+mf*16+qd*4+r; int mg=mt*128+ml;
      if(mg<1232){
        float v=acc[mf][nf][r]+bias;
        int bb=mg/77, l=mg-bb*77;
        if(ng<256) kb[((size_t)(bb*77+l))*256+ng]=f2bf(v);
        else vT[((size_t)(bb*256+(ng-256)))*96 + l]=f2bf(v);
      }
    }
  }
}

// ---------------- K7: attention per (b, 128-pixel q tile) ----------------
__global__ __launch_bounds__(256) void k_attn(const u16* __restrict__ qg, const u16* __restrict__ kb,
    const u16* __restrict__ vT, u16* __restrict__ ob){
  __shared__ u16 Qs[4096];        // 128 x 32
  __shared__ u16 KVs[4096];       // up to 128 x 32
  __shared__ u16 Sb[128*84];      // S scores, bf16, padded
  __shared__ u16 Pb[128*104];     // P, bf16, k-padded to 96 (+8)
  int bid=blockIdx.x; int b=bid>>5, qt=bid&31; int p0=qt*128;
  int tid=threadIdx.x, w=tid>>6, lane=tid&63, ln=lane&15, qd=lane>>4;
  int srow=tid>>2, koff=(tid&3)*8;
  f32x4 Sa[2][5]={};
  for(int kt=0;kt<8;kt++){
    for(int j=0;j<2;j++){
      int m=srow+j*64;
      g2l16(qg + ((size_t)(b*HW_+p0+m)*256 + kt*32+koff), &Qs[(size_t)tid*8+j*2048]);
    }
    for(int j=0;j<2;j++){
      int cja = tid + j*256;
      if(cja < 320){
        int l = cja>>2, ko2=(cja&3)*8;
        g2l16(kb + ((size_t)(b*77+l)*256 + kt*32+ko2), &KVs[(size_t)cja*8]);
      }
    }
    __syncthreads();
    bf16x8 af[2], bfv[5];
    for(int mf=0;mf<2;mf++) af[mf]=ldfrag(&Qs[(w*32+mf*16+ln)*32+qd*8]);
    for(int nf=0;nf<5;nf++) bfv[nf]=ldfrag(&KVs[(nf*16+ln)*32+qd*8]);
    for(int mf=0;mf<2;mf++) for(int nf=0;nf<5;nf++)
      Sa[mf][nf]=__builtin_amdgcn_mfma_f32_16x16x32_bf16(af[mf],bfv[nf],Sa[mf][nf],0,0,0);
    __syncthreads();
  }
  for(int mf=0;mf<2;mf++) for(int nf=0;nf<5;nf++) for(int r=0;r<4;r++){
    int ml=w*32+mf*16+qd*4+r, nl=nf*16+ln;
    Sb[ml*84+nl]=f2bf(Sa[mf][nf][r]*0.0625f);
  }
  __syncthreads();
  if(tid<128){
    const u16* srp = &Sb[tid*84];
    u16* prow = &Pb[tid*104];
    float mx=-1e30f;
    for(int j2=0;j2<77;j2++){ float v=bf2f(srp[j2]); mx=fmaxf(mx,v); }
    float sum=0.f;
    for(int j2=0;j2<77;j2++){ float e=__expf(bf2f(srp[j2])-mx); sum+=e; prow[j2]=f2bf(e); }
    float inv=1.f/sum;
    for(int j2=0;j2<77;j2++){ prow[j2]=f2bf(bf2f(prow[j2])*inv); }
    for(int j2=77;j2<104;j2++) prow[j2]=0;
  }
  __syncthreads();
  for(int nh=0;nh<2;nh++){
    f32x4 Oa[2][8]={};
    for(int kt2=0;kt2<3;kt2++){
      for(int j=0;j<2;j++){
        int chunk=tid+j*256;
        int co=chunk>>2, ko2=(chunk&3)*8;
        g2l16(vT + ((size_t)(b*256+nh*128+co)*96 + kt2*32+ko2), &KVs[(size_t)chunk*8]);
      }
      __syncthreads();
      bf16x8 af[2], bfv[8];
      for(int mf=0;mf<2;mf++) af[mf]=ldfrag(&Pb[(w*32+mf*16+ln)*104 + kt2*32+qd*8]);
      for(int nf=0;nf<8;nf++) bfv[nf]=ldfrag(&KVs[(nf*16+ln)*32+qd*8]);
      for(int mf=0;mf<2;mf++) for(int nf=0;nf<8;nf++)
        Oa[mf][nf]=__builtin_amdgcn_mfma_f32_16x16x32_bf16(af[mf],bfv[nf],Oa[mf][nf],0,0,0);
      __syncthreads();
    }
    for(int mf=0;mf<2;mf++) for(int nf=0;nf<8;nf++) for(int r=0;r<4;r++){
      int ml=w*32+mf*16+qd*4+r, nl=nh*128+nf*16+ln;
      ob[((size_t)(b*HW_+p0+ml))*256+nl]=f2bf(Oa[mf][nf][r]);
    }
  }
}

// ---------------- K8: out = x + (wo @ o^T) + bo, written NCHW (round-1 structure) -------
__global__ __launch_bounds__(256) void k_oproj(const u16* __restrict__ ob, const u16* __restrict__ woB,
    const float* __restrict__ bo, const float* __restrict__ x, float* __restrict__ outp){
  __shared__ u16 As[128*32];
  __shared__ u16 Bs[128*32];
  int bid=blockIdx.x;
  int b=bid>>6; int rr=bid&63; int cm=rr>>5, pt=rr&31;
  int c0=cm*128, p0=pt*128;
  int tid=threadIdx.x, w=tid>>6, lane=tid&63, ln=lane&15, qd=lane>>4, wm=w>>1, wn=w&1;
  int srow=tid>>2, koff=(tid&3)*8;
  f32x4 acc[4][4]={};
  for(int kt=0;kt<8;kt++){
    for(int j=0;j<2;j++){
      int m=srow+j*64;
      g2l16(woB + ((size_t)(c0+m)*256 + kt*32+koff),        &As[(size_t)tid*8+j*2048]);
      g2l16(ob  + ((size_t)(b*HW_+p0+m)*256 + kt*32+koff),  &Bs[(size_t)tid*8+j*2048]);
    }
    __syncthreads();
    bf16x8 af[4], bfv[4];
    for(int mf=0;mf<4;mf++) af[mf]=ldfrag(&As[(wm*64+mf*16+ln)*32+qd*8]);
    for(int nf=0;nf<4;nf++) bfv[nf]=ldfrag(&Bs[(wn*64+nf*16+ln)*32+qd*8]);
    for(int mf=0;mf<4;mf++) for(int nf=0;nf<4;nf++)
      acc[mf][nf]=__builtin_amdgcn_mfma_f32_16x16x32_bf16(af[mf],bfv[nf],acc[mf][nf],0,0,0);
    __syncthreads();
  }
  for(int mf=0;mf<4;mf++) for(int r=0;r<4;r++){
    int cl=c0+wm*64+mf*16+qd*4+r;
    float bias=bo[cl];
    for(int nf=0;nf<4;nf++){
      int pl=p0+wn*64+nf*16+ln;
      size_t idx=((size_t)(b*C_+cl))*HW_+pl;
      outp[idx]=x[idx]+acc[mf][nf][r]+bias;
    }
  }
}

extern "C" void kernel_launch(void* const* d_in, const int* in_sizes, int n_in,
                              void* d_out, int out_size, void* d_ws, size_t ws_size,
                              hipStream_t stream){
  const float* x      = (const float*)d_in[0];
  const float* ctx    = (const float*)d_in[1];
  const float* conv_w = (const float*)d_in[2];
  const float* conv_b = (const float*)d_in[3];
  const float* gnw    = (const float*)d_in[4];
  const float* gnb    = (const float*)d_in[5];
  const float* wq     = (const float*)d_in[6];
  const float* bq     = (const float*)d_in[7];
  const float* wk     = (const float*)d_in[8];
  const float* bk     = (const float*)d_in[9];
  const float* wv     = (const float*)d_in[10];
  const float* bv     = (const float*)d_in[11];
  const float* wo     = (const float*)d_in[12];
  const float* bo     = (const float*)d_in[13];
  char* ws = (char*)d_ws;
  u16* xpT  = (u16*)(ws + 0);            // 35,684,352 ; reused as q after conv
  u16* wBt  = (u16*)(ws + 35684352);     //  1,179,648
  u16* wqB  = (u16*)(ws + 36864000);     //    131,072
  u16* wkvB = (u16*)(ws + 36995072);     //    786,432
  u16* woB  = (u16*)(ws + 37781504);     //    131,072
  u16* ctxB = (u16*)(ws + 37912576);     //  1,892,352
  u16* hbuf = (u16*)(ws + 39804928);     // 33,554,432 (h, then hf in place)
  u16* kbv  = (u16*)(ws + 73359360);     //    630,784
  u16* vT   = (u16*)(ws + 73990144);     //    786,432
  u16* obuf = (u16*)(ws + 74776576);     // 33,554,432
  float* stats = (float*)(ws + 108331008); // 2048
  u16* qb = xpT;
  float* outp = (float*)d_out;

  k_pad   <<<1056, 256, 0, stream>>>(x, xpT);
  k_repack<<<8050, 256, 0, stream>>>(conv_w, wq, wo, wk, wv, ctx, wBt, wqB, woB, wkvB, ctxB, stats);
  k_conv  <<<512,  256, 0, stream>>>(xpT, wBt, conv_b, hbuf, stats);
  k_stats <<<1,    128, 0, stream>>>(stats);
  k_gnsilu<<<16384,256, 0, stream>>>(hbuf, stats, gnw, gnb);
  k_qproj <<<1024, 256, 0, stream>>>(hbuf, wqB, bq, qb);
  k_kvproj<<<40,   256, 0, stream>>>(ctxB, wkvB, bk, bv, kbv, vT);
  k_attn  <<<512,  256, 0, stream>>>(qb, kbv, vT, obuf);
  k_oproj <<<1024, 256, 0, stream>>>(obuf, woB, bo, x, outp);
}

// Round 5
// 385.293 us; speedup vs baseline: 1.5301x; 1.2743x over previous
//
#include <hip/hip_runtime.h>
#include <stdint.h>

#define B_  16
#define C_  256
#define HW_ 4096
#define Hp  66
#define PP  4356   // 66*66
#define EPS_ 1e-5f

typedef unsigned short u16;
typedef unsigned int   u32;
typedef __attribute__((ext_vector_type(4))) float  f32x4;
typedef __attribute__((ext_vector_type(8))) __bf16 bf16x8;
typedef __attribute__((ext_vector_type(8))) u16    u16x8;

__device__ __forceinline__ float bf2f(u16 u){ u32 x = ((u32)u)<<16; float f; __builtin_memcpy(&f,&x,4); return f; }
__device__ __forceinline__ u16 f2bf(float f){ u32 x; __builtin_memcpy(&x,&f,4); u32 r = x + 0x7fffu + ((x>>16)&1u); return (u16)(r>>16); }

__device__ __forceinline__ void g2l16(const void* g, void* l){
  __builtin_amdgcn_global_load_lds((__attribute__((address_space(1))) void*)(void*)g,
                                   (__attribute__((address_space(3))) void*)l, 16, 0, 0);
}
__device__ __forceinline__ bf16x8 ldfrag(const u16* p){
  u16x8 r = *(const u16x8*)p;
  return __builtin_bit_cast(bf16x8, r);
}

// ---------------- K0: pad + transpose + cast x -> xpT[b][66*66][256] bf16 ----------------
__global__ __launch_bounds__(256) void k_pad(const float* __restrict__ x, u16* __restrict__ xpT){
  int bid = blockIdx.x; int b = bid/66, hh = bid - b*66; int tid = threadIdx.x;
  u16* rowbase = xpT + (size_t)(b*PP + hh*Hp)*C_;
  if(hh==0 || hh==65){
    u32* p = (u32*)rowbase;
    for(int i=tid;i<66*C_/2;i+=256) p[i]=0u;
    return;
  }
  if(tid<128) ((u32*)rowbase)[tid]=0u;                 // ww = 0 border
  else ((u32*)(rowbase + 65*C_))[tid-128]=0u;          // ww = 65 border
  int h = hh-1;
  __shared__ float Lt[64*65];
  for(int cc=0; cc<4; cc++){
    int c0=cc*64;
    int ci = tid>>2, w0 = (tid&3)*16;
    const float* xs = x + ((size_t)(b*C_ + c0+ci)*HW_) + h*64 + w0;
    for(int j=0;j<4;j++){
      float4 v = *(const float4*)(xs + j*4);
      Lt[ci*65 + w0 + j*4 + 0] = v.x;
      Lt[ci*65 + w0 + j*4 + 1] = v.y;
      Lt[ci*65 + w0 + j*4 + 2] = v.z;
      Lt[ci*65 + w0 + j*4 + 3] = v.w;
    }
    __syncthreads();
    int w = tid>>2, cj = (tid&3)*16;
    union { u16 u[16]; uint4 v[2]; } outu;
    for(int j=0;j<16;j++) outu.u[j] = f2bf(Lt[(cj+j)*65 + w]);
    uint4* dst = (uint4*)(rowbase + (size_t)(w+1)*C_ + c0 + cj);
    dst[0]=outu.v[0]; dst[1]=outu.v[1];
    __syncthreads();
  }
}

// ---------------- K1: repack weights/context to bf16, zero stats ----------------
__global__ __launch_bounds__(256) void k_repack(
    const float* __restrict__ conv_w, const float* __restrict__ wq, const float* __restrict__ wo,
    const float* __restrict__ wk, const float* __restrict__ wv, const float* __restrict__ ctx,
    u16* __restrict__ wBt, u16* __restrict__ wqB, u16* __restrict__ woB,
    u16* __restrict__ wkvB, u16* __restrict__ ctxB, float* __restrict__ stats){
  int i = blockIdx.x*256 + threadIdx.x;
  if(i < 589824){ int co = i/2304, k = i - co*2304; int t = k>>8, ci = k&255;
    wBt[i] = f2bf(conv_w[(co*256+ci)*9 + t]); return; }
  i -= 589824;
  if(i < 65536){ wqB[i] = f2bf(wq[i]); return; } i -= 65536;
  if(i < 65536){ woB[i] = f2bf(wo[i]); return; } i -= 65536;
  if(i < 196608){ wkvB[i] = f2bf(wk[i]); return; } i -= 196608;
  if(i < 196608){ wkvB[196608+i] = f2bf(wv[i]); return; } i -= 196608;
  if(i < 946176){ ctxB[i] = f2bf(ctx[i]); return; } i -= 946176;
  if(i < 512){ stats[i] = 0.f; }
}

// ---------------- K2: conv implicit GEMM, A-slab resident across taps ----------------
__global__ __launch_bounds__(256, 2) void k_conv(const u16* __restrict__ xpT, const u16* __restrict__ wBt,
    const float* __restrict__ conv_b, u16* __restrict__ h, float* __restrict__ stats){
  __shared__ u16 As[264*32];
  __shared__ u16 Bs[256*32];
  int bid = blockIdx.x;
  int b = bid >> 5, hp = bid & 31;
  int tid = threadIdx.x;
  int w = tid>>6, lane = tid&63, ln = lane&15, qd = lane>>4;
  int wm = w&1, wn = w>>1;
  const u16* Abase = xpT + (size_t)(b*PP + hp*132)*C_;
  f32x4 acc[4][8] = {};
  int hr_[4], wp_[4];
  #pragma unroll
  for(int mf=0;mf<4;mf++){ int p = wm*64 + mf*16 + ln; hr_[mf] = p>>6; wp_[mf] = p&63; }

  for(int ci=0; ci<8; ci++){
    int ci0 = ci*32;
    #pragma unroll
    for(int r=0;r<5;r++){
      int c = r*256 + tid;
      if(c < 1056){
        int ipix = c>>2, atom = c&3;
        g2l16(Abase + (size_t)ipix*C_ + ci0 + atom*8, &As[c*8]);
      }
    }
    for(int t=0;t<9;t++){
      int dy = (t*11)>>5, dx = t - dy*3;
      #pragma unroll
      for(int r=0;r<4;r++){
        int c = r*256 + tid;
        int co = c>>2, atom = c&3;
        g2l16(wBt + (size_t)co*2304 + t*256 + ci0 + atom*8, &Bs[c*8]);
      }
      __syncthreads();
      bf16x8 af[4], bfv[8];
      #pragma unroll
      for(int mf=0;mf<4;mf++){
        int ipix = (hr_[mf]+dy)*66 + wp_[mf] + dx;
        af[mf] = ldfrag(&As[ipix*32 + qd*8]);
      }
      #pragma unroll
      for(int nf=0;nf<8;nf++) bfv[nf] = ldfrag(&Bs[(wn*128+nf*16+ln)*32 + qd*8]);
      #pragma unroll
      for(int mf=0;mf<4;mf++)
        #pragma unroll
        for(int nf=0;nf<8;nf++)
          acc[mf][nf] = __builtin_amdgcn_mfma_f32_16x16x32_bf16(af[mf], bfv[nf], acc[mf][nf], 0,0,0);
      __syncthreads();
    }
  }
  float s[4]={0,0,0,0}, q[4]={0,0,0,0};
  int p0 = hp*128;
  for(int nf=0;nf<8;nf++){
    int n = wn*128 + nf*16 + ln;
    float bias = conv_b[n];
    for(int mf=0;mf<4;mf++){
      for(int r=0;r<4;r++){
        int p = wm*64 + mf*16 + qd*4 + r;
        float v = acc[mf][nf][r] + bias;
        h[((size_t)(b*HW_ + p0 + p))*C_ + n] = f2bf(v);
        s[nf>>1]+=v; q[nf>>1]+=v*v;
      }
    }
  }
  for(int off=32;off>=1;off>>=1){
    #pragma unroll
    for(int g=0;g<4;g++){ s[g]+=__shfl_down(s[g],off,64); q[g]+=__shfl_down(q[g],off,64); }
  }
  if(lane==0){
    #pragma unroll
    for(int g=0;g<4;g++){
      atomicAdd(&stats[(b*8 + wn*4 + g)*2+0], s[g]);
      atomicAdd(&stats[(b*8 + wn*4 + g)*2+1], q[g]);
    }
  }
}

// ---------------- K4: GN + SiLU, in place on h (stats finalize fused) ----------------
__global__ __launch_bounds__(256) void k_gnsilu(u16* __restrict__ hbuf, const float* __restrict__ stats,
      const float* __restrict__ gnw, const float* __restrict__ gnb){
  size_t i = ((size_t)blockIdx.x*256 + threadIdx.x)*4;
  int c0 = (int)(i & 255);
  size_t row = i >> 8;
  int b = (int)(row >> 12);
  int g = c0 >> 5;
  float sm = stats[(b*8+g)*2], qm = stats[(b*8+g)*2+1];
  float mean = sm*(1.f/131072.f);
  float var  = qm*(1.f/131072.f) - mean*mean;
  float rstd = rsqrtf(var + EPS_);
  u32* p = (u32*)(hbuf + i);
  u32 v0 = p[0], v1 = p[1];
  u16 in[4] = {(u16)(v0&0xffff),(u16)(v0>>16),(u16)(v1&0xffff),(u16)(v1>>16)};
  u16 outv[4];
  for(int j=0;j<4;j++){
    float v = bf2f(in[j]);
    v = (v-mean)*rstd*gnw[c0+j] + gnb[c0+j];
    float s = v/(1.f+__expf(-v));
    outv[j] = f2bf(s);
  }
  p[0] = (u32)outv[0] | ((u32)outv[1]<<16);
  p[1] = (u32)outv[2] | ((u32)outv[3]<<16);
}

// ---------------- K5: q = hf @ wq^T + bq ----------------
__global__ __launch_bounds__(256) void k_qproj(const u16* __restrict__ hf, const u16* __restrict__ wqB,
    const float* __restrict__ bq, u16* __restrict__ qb){
  __shared__ u16 As[128*32];
  __shared__ u16 Bs[128*32];
  int bid = blockIdx.x;
  int nt = bid & 1, mt = bid >> 1;
  int co0 = nt*128;
  int tid = threadIdx.x;
  int w=tid>>6, lane=tid&63, ln=lane&15, qd=lane>>4, wm=w>>1, wn=w&1;
  int srow=tid>>2, koff=(tid&3)*8;
  f32x4 acc[4][4] = {};
  for(int kt=0;kt<8;kt++){
    for(int j=0;j<2;j++){
      int m = srow + j*64;
      g2l16(hf  + ((size_t)(mt*128+m)*256 + kt*32 + koff), &As[(size_t)tid*8 + j*2048]);
      g2l16(wqB + ((size_t)(co0+m)*256 + kt*32 + koff),    &Bs[(size_t)tid*8 + j*2048]);
    }
    __syncthreads();
    bf16x8 af[4], bfv[4];
    for(int mf=0;mf<4;mf++) af[mf]=ldfrag(&As[(wm*64+mf*16+ln)*32+qd*8]);
    for(int nf=0;nf<4;nf++) bfv[nf]=ldfrag(&Bs[(wn*64+nf*16+ln)*32+qd*8]);
    for(int mf=0;mf<4;mf++) for(int nf=0;nf<4;nf++)
      acc[mf][nf]=__builtin_amdgcn_mfma_f32_16x16x32_bf16(af[mf],bfv[nf],acc[mf][nf],0,0,0);
    __syncthreads();
  }
  for(int mf=0;mf<4;mf++) for(int nf=0;nf<4;nf++){
    int nl=wn*64+nf*16+ln; float bias=bq[co0+nl];
    for(int r=0;r<4;r++){
      int ml=wm*64+mf*16+qd*4+r;
      qb[((size_t)(mt*128+ml))*256 + co0+nl] = f2bf(acc[mf][nf][r]+bias);
    }
  }
}

// ---------------- K6: k,v = ctx @ {wk,wv}^T + b, 64x64 tiles, 160 blocks ----------------
// kb[b][77][256], vT[b][256][96]
__global__ __launch_bounds__(256) void k_kvproj(const u16* __restrict__ ctxB, const u16* __restrict__ wkvB,
    const float* __restrict__ bk, const float* __restrict__ bv,
    u16* __restrict__ kb, u16* __restrict__ vT){
  __shared__ u16 As[64*128];
  __shared__ u16 Bs[64*128];
  int bid = blockIdx.x;
  int nt = bid & 7, mt = bid >> 3;
  int n0 = nt*64, m0 = mt*64;
  int tid=threadIdx.x, w=tid>>6, lane=tid&63, ln=lane&15, qd=lane>>4;
  int wm = w&1, wn = w>>1;
  f32x4 acc[2][2]={};
  for(int kt=0;kt<6;kt++){
    #pragma unroll
    for(int r=0;r<4;r++){
      int c = r*256 + tid;
      int row = c>>4, atom = c&15;
      g2l16(ctxB + ((size_t)(m0+row)*768 + kt*128 + atom*8), &As[c*8]);
      g2l16(wkvB + ((size_t)(n0+row)*768 + kt*128 + atom*8), &Bs[c*8]);
    }
    __syncthreads();
    #pragma unroll
    for(int kk=0;kk<4;kk++){
      bf16x8 af[2], bfv[2];
      #pragma unroll
      for(int mf=0;mf<2;mf++) af[mf]=ldfrag(&As[(wm*32+mf*16+ln)*128 + kk*32 + qd*8]);
      #pragma unroll
      for(int nf=0;nf<2;nf++) bfv[nf]=ldfrag(&Bs[(wn*32+nf*16+ln)*128 + kk*32 + qd*8]);
      #pragma unroll
      for(int mf=0;mf<2;mf++)
        #pragma unroll
        for(int nf=0;nf<2;nf++)
          acc[mf][nf]=__builtin_amdgcn_mfma_f32_16x16x32_bf16(af[mf],bfv[nf],acc[mf][nf],0,0,0);
    }
    __syncthreads();
  }
  for(int mf=0;mf<2;mf++) for(int nf=0;nf<2;nf++){
    int ng = n0 + wn*32 + nf*16 + ln;
    float bias = ng<256 ? bk[ng] : bv[ng-256];
    for(int r=0;r<4;r++){
      int mg = m0 + wm*32 + mf*16 + qd*4 + r;
      if(mg<1232){
        float v=acc[mf][nf][r]+bias;
        int bb=mg/77, l=mg-bb*77;
        if(ng<256) kb[((size_t)(bb*77+l))*256+ng]=f2bf(v);
        else vT[((size_t)(bb*256+(ng-256)))*96 + l]=f2bf(v);
      }
    }
  }
}

// ---------------- K7: attention per (b, 128-pixel q tile) ----------------
__global__ __launch_bounds__(256) void k_attn(const u16* __restrict__ qg, const u16* __restrict__ kb,
    const u16* __restrict__ vT, u16* __restrict__ ob){
  __shared__ u16 Qs[4096];        // 128 x 32
  __shared__ u16 KVs[4096];       // up to 128 x 32
  __shared__ u16 Sb[128*84];      // S scores, bf16, padded
  __shared__ u16 Pb[128*104];     // P, bf16, k-padded to 96 (+8)
  int bid=blockIdx.x; int b=bid>>5, qt=bid&31; int p0=qt*128;
  int tid=threadIdx.x, w=tid>>6, lane=tid&63, ln=lane&15, qd=lane>>4;
  int srow=tid>>2, koff=(tid&3)*8;
  f32x4 Sa[2][5]={};
  for(int kt=0;kt<8;kt++){
    for(int j=0;j<2;j++){
      int m=srow+j*64;
      g2l16(qg + ((size_t)(b*HW_+p0+m)*256 + kt*32+koff), &Qs[(size_t)tid*8+j*2048]);
    }
    for(int j=0;j<2;j++){
      int cja = tid + j*256;
      if(cja < 320){
        int l = cja>>2, ko2=(cja&3)*8;
        g2l16(kb + ((size_t)(b*77+l)*256 + kt*32+ko2), &KVs[(size_t)cja*8]);
      }
    }
    __syncthreads();
    bf16x8 af[2], bfv[5];
    for(int mf=0;mf<2;mf++) af[mf]=ldfrag(&Qs[(w*32+mf*16+ln)*32+qd*8]);
    for(int nf=0;nf<5;nf++) bfv[nf]=ldfrag(&KVs[(nf*16+ln)*32+qd*8]);
    for(int mf=0;mf<2;mf++) for(int nf=0;nf<5;nf++)
      Sa[mf][nf]=__builtin_amdgcn_mfma_f32_16x16x32_bf16(af[mf],bfv[nf],Sa[mf][nf],0,0,0);
    __syncthreads();
  }
  for(int mf=0;mf<2;mf++) for(int nf=0;nf<5;nf++) for(int r=0;r<4;r++){
    int ml=w*32+mf*16+qd*4+r, nl=nf*16+ln;
    Sb[ml*84+nl]=f2bf(Sa[mf][nf][r]*0.0625f);
  }
  __syncthreads();
  if(tid<128){
    const u16* srp = &Sb[tid*84];
    u16* prow = &Pb[tid*104];
    float mx=-1e30f;
    for(int j2=0;j2<77;j2++){ float v=bf2f(srp[j2]); mx=fmaxf(mx,v); }
    float sum=0.f;
    for(int j2=0;j2<77;j2++){ float e=__expf(bf2f(srp[j2])-mx); sum+=e; prow[j2]=f2bf(e); }
    float inv=1.f/sum;
    for(int j2=0;j2<77;j2++){ prow[j2]=f2bf(bf2f(prow[j2])*inv); }
    for(int j2=77;j2<104;j2++) prow[j2]=0;
  }
  __syncthreads();
  for(int nh=0;nh<2;nh++){
    f32x4 Oa[2][8]={};
    for(int kt2=0;kt2<3;kt2++){
      for(int j=0;j<2;j++){
        int chunk=tid+j*256;
        int co=chunk>>2, ko2=(chunk&3)*8;
        g2l16(vT + ((size_t)(b*256+nh*128+co)*96 + kt2*32+ko2), &KVs[(size_t)chunk*8]);
      }
      __syncthreads();
      bf16x8 af[2], bfv[8];
      for(int mf=0;mf<2;mf++) af[mf]=ldfrag(&Pb[(w*32+mf*16+ln)*104 + kt2*32+qd*8]);
      for(int nf=0;nf<8;nf++) bfv[nf]=ldfrag(&KVs[(nf*16+ln)*32+qd*8]);
      for(int mf=0;mf<2;mf++) for(int nf=0;nf<8;nf++)
        Oa[mf][nf]=__builtin_amdgcn_mfma_f32_16x16x32_bf16(af[mf],bfv[nf],Oa[mf][nf],0,0,0);
      __syncthreads();
    }
    for(int mf=0;mf<2;mf++) for(int nf=0;nf<8;nf++) for(int r=0;r<4;r++){
      int ml=w*32+mf*16+qd*4+r, nl=nh*128+nf*16+ln;
      ob[((size_t)(b*HW_+p0+ml))*256+nl]=f2bf(Oa[mf][nf][r]);
    }
  }
}

// ---------------- K8: out = x + (wo @ o^T) + bo, written NCHW ----------------
__global__ __launch_bounds__(256) void k_oproj(const u16* __restrict__ ob, const u16* __restrict__ woB,
    const float* __restrict__ bo, const float* __restrict__ x, float* __restrict__ outp){
  __shared__ u16 As[128*32];
  __shared__ u16 Bs[128*32];
  int bid=blockIdx.x;
  int b=bid>>6; int rr=bid&63; int cm=rr>>5, pt=rr&31;
  int c0=cm*128, p0=pt*128;
  int tid=threadIdx.x, w=tid>>6, lane=tid&63, ln=lane&15, qd=lane>>4, wm=w>>1, wn=w&1;
  int srow=tid>>2, koff=(tid&3)*8;
  f32x4 acc[4][4]={};
  for(int kt=0;kt<8;kt++){
    for(int j=0;j<2;j++){
      int m=srow+j*64;
      g2l16(woB + ((size_t)(c0+m)*256 + kt*32+koff),        &As[(size_t)tid*8+j*2048]);
      g2l16(ob  + ((size_t)(b*HW_+p0+m)*256 + kt*32+koff),  &Bs[(size_t)tid*8+j*2048]);
    }
    __syncthreads();
    bf16x8 af[4], bfv[4];
    for(int mf=0;mf<4;mf++) af[mf]=ldfrag(&As[(wm*64+mf*16+ln)*32+qd*8]);
    for(int nf=0;nf<4;nf++) bfv[nf]=ldfrag(&Bs[(wn*64+nf*16+ln)*32+qd*8]);
    for(int mf=0;mf<4;mf++) for(int nf=0;nf<4;nf++)
      acc[mf][nf]=__builtin_amdgcn_mfma_f32_16x16x32_bf16(af[mf],bfv[nf],acc[mf][nf],0,0,0);
    __syncthreads();
  }
  for(int mf=0;mf<4;mf++) for(int r=0;r<4;r++){
    int cl=c0+wm*64+mf*16+qd*4+r;
    float bias=bo[cl];
    for(int nf=0;nf<4;nf++){
      int pl=p0+wn*64+nf*16+ln;
      size_t idx=((size_t)(b*C_+cl))*HW_+pl;
      outp[idx]=x[idx]+acc[mf][nf][r]+bias;
    }
  }
}

extern "C" void kernel_launch(void* const* d_in, const int* in_sizes, int n_in,
                              void* d_out, int out_size, void* d_ws, size_t ws_size,
                              hipStream_t stream){
  const float* x      = (const float*)d_in[0];
  const float* ctx    = (const float*)d_in[1];
  const float* conv_w = (const float*)d_in[2];
  const float* conv_b = (const float*)d_in[3];
  const float* gnw    = (const float*)d_in[4];
  const float* gnb    = (const float*)d_in[5];
  const float* wq     = (const float*)d_in[6];
  const float* bq     = (const float*)d_in[7];
  const float* wk     = (const float*)d_in[8];
  const float* bk     = (const float*)d_in[9];
  const float* wv     = (const float*)d_in[10];
  const float* bv     = (const float*)d_in[11];
  const float* wo     = (const float*)d_in[12];
  const float* bo     = (const float*)d_in[13];
  char* ws = (char*)d_ws;
  u16* xpT  = (u16*)(ws + 0);            // 35,684,352 ; reused as q after conv
  u16* wBt  = (u16*)(ws + 35684352);     //  1,179,648
  u16* wqB  = (u16*)(ws + 36864000);     //    131,072
  u16* wkvB = (u16*)(ws + 36995072);     //    786,432
  u16* woB  = (u16*)(ws + 37781504);     //    131,072
  u16* ctxB = (u16*)(ws + 37912576);     //  1,892,352 (+74KB OOB read slack into hbuf)
  u16* hbuf = (u16*)(ws + 39804928);     // 33,554,432 (h, then hf in place)
  u16* kbv  = (u16*)(ws + 73359360);     //    630,784
  u16* vT   = (u16*)(ws + 73990144);     //    786,432
  u16* obuf = (u16*)(ws + 74776576);     // 33,554,432
  float* stats = (float*)(ws + 108331008); // 2048
  u16* qb = xpT;
  float* outp = (float*)d_out;

  k_pad   <<<1056, 256, 0, stream>>>(x, xpT);
  k_repack<<<8050, 256, 0, stream>>>(conv_w, wq, wo, wk, wv, ctx, wBt, wqB, woB, wkvB, ctxB, stats);
  k_conv  <<<512,  256, 0, stream>>>(xpT, wBt, conv_b, hbuf, stats);
  k_gnsilu<<<16384,256, 0, stream>>>(hbuf, stats, gnw, gnb);
  k_qproj <<<1024, 256, 0, stream>>>(hbuf, wqB, bq, qb);
  k_kvproj<<<160,  256, 0, stream>>>(ctxB, wkvB, bk, bv, kbv, vT);
  k_attn  <<<512,  256, 0, stream>>>(qb, kbv, vT, obuf);
  k_oproj <<<1024, 256, 0, stream>>>(obuf, woB, bo, x, outp);
}